// Round 5
// baseline (407.496 us; speedup 1.0000x reference)
//
#include <hip/hip_runtime.h>

// Koopman bilinear rollout: preds[b,t,d] = (z0 @ Kd^{t+1})[b,d], D=B=256, T=512.
// Kd = (I-A)^-1(I+A), A=0.5*dt*K -> order-4 Neumann: Kd = (I+P)@S + I,
// P = A@A, S = 2A+2P (exactly I+2A+2A^2+2A^3+2A^4, proven numerics).
// ONE persistent kernel (256 blocks, resident-grid barriers) builds:
//   N1, N2, M_j=Kd^j (j=1..32, 5 doublings), MTb (bf16 transpose),
//   checkpoint scan Z_i=z0@Kd^{32i} (i=1..15) with W-squarings folded in.
// Then one batched bf16-MFMA fill launch covers the remaining 497 timesteps.

#define DD 256
#define TT 512
#define MATF (DD * DD)
#define LDT ((size_t)TT * (size_t)DD)

typedef __attribute__((ext_vector_type(8))) short bf16x8;
typedef __attribute__((ext_vector_type(4))) float f32x4;

#define GLD16(g, l)                                                  \
    __builtin_amdgcn_global_load_lds(                                \
        (const __attribute__((address_space(1))) void*)(g),          \
        (__attribute__((address_space(3))) void*)(l), 16, 0, 0)

static __device__ __forceinline__ unsigned short f2bf(float f) {
    unsigned int u = __float_as_uint(f);
    u += 0x7fffu + ((u >> 16) & 1u);
    return (unsigned short)(u >> 16);
}

// ---------------- resident-grid barrier (slot + master broadcast) -----------
// bar[0..255]: per-block arrival slots (monotonic phase numbers)
// bar[256]   : generation broadcast
__device__ __forceinline__ void gridbar(unsigned* bar, int phase) {
    __syncthreads();  // all waves' stores drained to L2 (vmcnt0 before barrier)
    if (threadIdx.x == 0)
        __hip_atomic_store(&bar[blockIdx.x], (unsigned)phase, __ATOMIC_RELEASE,
                           __HIP_MEMORY_SCOPE_AGENT);
    if (blockIdx.x == 0) {
        for (unsigned s = threadIdx.x; s < gridDim.x; s += blockDim.x) {
            while (__hip_atomic_load(&bar[s], __ATOMIC_ACQUIRE,
                                     __HIP_MEMORY_SCOPE_AGENT) < (unsigned)phase)
                __builtin_amdgcn_s_sleep(2);
        }
        __syncthreads();
        if (threadIdx.x == 0)
            __hip_atomic_store(&bar[256], (unsigned)phase, __ATOMIC_RELEASE,
                               __HIP_MEMORY_SCOPE_AGENT);
    }
    if (threadIdx.x == 0) {
        while (__hip_atomic_load(&bar[256], __ATOMIC_ACQUIRE,
                                 __HIP_MEMORY_SCOPE_AGENT) < (unsigned)phase)
            __builtin_amdgcn_s_sleep(2);
    }
    __syncthreads();
}

__global__ void binit_kernel(unsigned* bar) {
    int i = threadIdx.x;
    if (i < 257) bar[i] = 0;
}

// ---------------- wave-level 32x16-tile f32 GEMM (K=256, K_BLK=64) ----------
// Af [64][36] (k-major), Bf [64][20]; wave-private -> no block barriers.
// amode: 0 plain A[r][k] ; 1 cs*A[r][k] ; 2 A[r][k] + (r==k)
// bmode: 0 plain B[k][c] ; 1 cs*B[k][c] ; 2 2*(cs*B[k][c] + Pq[k][c])
__device__ void gtile_compute(const float* A, size_t lda,
                              const float* B, size_t ldb,
                              const float* Pq, float cs, int amode, int bmode,
                              float* Af, float* Bf,
                              int tr, int tc, int lane, float acc[4][2]) {
    const int ar = lane & 31;        // A tile row
    const int akq = lane >> 5;       // A k-half
    const int bk = lane >> 2;        // B k-row (0..15)
    const int bc = (lane & 3) << 2;  // B col group

#pragma unroll
    for (int i = 0; i < 4; ++i) { acc[i][0] = 0.f; acc[i][1] = 0.f; }

    float4 pa[8], pb[4], pc[4];

#pragma unroll
    for (int q = 0; q < 8; ++q)
        pa[q] = *(const float4*)(A + (size_t)(tr + ar) * lda + q * 8 + akq * 4);
#pragma unroll
    for (int q = 0; q < 4; ++q) {
        pb[q] = *(const float4*)(B + (size_t)(q * 16 + bk) * ldb + tc + bc);
        if (bmode == 2)
            pc[q] = *(const float4*)(Pq + (size_t)(q * 16 + bk) * DD + tc + bc);
    }

    for (int k0 = 0; k0 < DD; k0 += 64) {
#pragma unroll
        for (int q = 0; q < 8; ++q) {
            int kb = q * 8 + akq * 4;
            float v[4] = {pa[q].x, pa[q].y, pa[q].z, pa[q].w};
#pragma unroll
            for (int i = 0; i < 4; ++i) {
                float x = v[i];
                if (amode == 1) x *= cs;
                else if (amode == 2) x += ((k0 + kb + i) == (tr + ar)) ? 1.f : 0.f;
                Af[(kb + i) * 36 + ar] = x;
            }
        }
#pragma unroll
        for (int q = 0; q < 4; ++q) {
            int kb = q * 16 + bk;
            float4 o = pb[q];
            float* op = (float*)&o;
            if (bmode == 1) {
                op[0] *= cs; op[1] *= cs; op[2] *= cs; op[3] *= cs;
            } else if (bmode == 2) {
                const float* wp = (const float*)&pc[q];
#pragma unroll
                for (int i = 0; i < 4; ++i) op[i] = 2.f * (cs * op[i] + wp[i]);
            }
            *(float4*)(Bf + kb * 20 + bc) = o;
        }
        if (k0 + 64 < DD) {  // register prefetch of next round
#pragma unroll
            for (int q = 0; q < 8; ++q)
                pa[q] = *(const float4*)(A + (size_t)(tr + ar) * lda + k0 + 64 +
                                         q * 8 + akq * 4);
#pragma unroll
            for (int q = 0; q < 4; ++q) {
                pb[q] = *(const float4*)(B + (size_t)(k0 + 64 + q * 16 + bk) * ldb +
                                         tc + bc);
                if (bmode == 2)
                    pc[q] = *(const float4*)(Pq + (size_t)(k0 + 64 + q * 16 + bk) * DD +
                                             tc + bc);
            }
        }
        const int ty4 = (lane >> 3) << 2;
        const int tx2 = (lane & 7) << 1;
#pragma unroll
        for (int kk = 0; kk < 64; ++kk) {
            float4 a4 = *(const float4*)(Af + kk * 36 + ty4);
            float2 b2 = *(const float2*)(Bf + kk * 20 + tx2);
            acc[0][0] = fmaf(a4.x, b2.x, acc[0][0]);
            acc[0][1] = fmaf(a4.x, b2.y, acc[0][1]);
            acc[1][0] = fmaf(a4.y, b2.x, acc[1][0]);
            acc[1][1] = fmaf(a4.y, b2.y, acc[1][1]);
            acc[2][0] = fmaf(a4.z, b2.x, acc[2][0]);
            acc[2][1] = fmaf(a4.z, b2.y, acc[2][1]);
            acc[3][0] = fmaf(a4.w, b2.x, acc[3][0]);
            acc[3][1] = fmaf(a4.w, b2.y, acc[3][1]);
        }
    }
}

__device__ __forceinline__ void epi_plain(float* C, int ldc, int tr, int tc,
                                          int lane, float acc[4][2], int addI) {
    const int r0 = tr + ((lane >> 3) << 2);
    const int c0 = tc + ((lane & 7) << 1);
#pragma unroll
    for (int i = 0; i < 4; ++i) {
        int r = r0 + i;
        float2 v = {acc[i][0], acc[i][1]};
        if (addI) {
            v.x += (r == c0) ? 1.f : 0.f;
            v.y += (r == c0 + 1) ? 1.f : 0.f;
        }
        *(float2*)(C + (size_t)r * ldc + c0) = v;
    }
}

__device__ __forceinline__ void epi_v(float* out, unsigned short* Zb, int dst,
                                      int tr, int tc, int lane, float acc[4][2]) {
    float* Of = out + (size_t)(32 * dst - 1) * DD;
    unsigned short* Zo = Zb + (size_t)dst * MATF;
    const int r0 = tr + ((lane >> 3) << 2);
    const int c0 = tc + ((lane & 7) << 1);
#pragma unroll
    for (int i = 0; i < 4; ++i) {
        int r = r0 + i;
        float2 v = {acc[i][0], acc[i][1]};
        *(float2*)(Of + (size_t)r * LDT + c0) = v;
        unsigned w = (unsigned)f2bf(v.x) | ((unsigned)f2bf(v.y) << 16);
        *(unsigned*)(Zo + (size_t)r * DD + c0) = w;
    }
}

// ---------------- persistent table kernel (all 12 phases, 1 launch) ---------
__global__ void __launch_bounds__(256, 1)
tabs_kernel(const float* __restrict__ z0, const float* __restrict__ Kmat,
            const float* __restrict__ log_dt, float* __restrict__ out,
            float* __restrict__ Mtab, float* __restrict__ Wtab,
            float* __restrict__ Pmat, unsigned short* __restrict__ MTb,
            unsigned short* __restrict__ Zb, unsigned* bar) {
    __shared__ __align__(16) float pool[4][64 * 36 + 64 * 20];
    const int tid = threadIdx.x;
    const int lane = tid & 63, wid = tid >> 6;
    float* Af = pool[wid];
    float* Bf = Af + 64 * 36;
    const int wgid = blockIdx.x * 4 + wid;  // 0..1023
    const float cs = 0.5f * expf(log_dt[0]);
    float acc[4][2];

    // ph1: Zb[0] = bf16(z0)  and  N1: P = (cs*K)@(cs*K)
    {
        int idx = blockIdx.x * 256 + tid;
        Zb[idx] = f2bf(z0[idx]);
        for (int tj = wgid; tj < 128; tj += 1024) {
            int tr = (tj >> 4) << 5, tc = (tj & 15) << 4;
            gtile_compute(Kmat, DD, Kmat, DD, nullptr, cs, 1, 1, Af, Bf, tr, tc,
                          lane, acc);
            epi_plain(Pmat, DD, tr, tc, lane, acc, 0);
        }
    }
    gridbar(bar, 1);

    // ph2: N2: Kd = (I+P)@S + I, S = 2*(cs*K + P)   -> Mtab[0]
    for (int tj = wgid; tj < 128; tj += 1024) {
        int tr = (tj >> 4) << 5, tc = (tj & 15) << 4;
        gtile_compute(Pmat, DD, Kmat, DD, Pmat, cs, 2, 2, Af, Bf, tr, tc, lane, acc);
        epi_plain(Mtab, DD, tr, tc, lane, acc, 1);
    }
    gridbar(bar, 2);

    // ph3..7: M doublings: M_{mm+1+p} = M_{mm+1} @ M_p
    for (int L = 0; L < 5; ++L) {
        int p = 1 << L;
        for (int tj = wgid; tj < 128 * p; tj += 1024) {
            int mm = tj >> 7, t = tj & 127;
            int tr = (t >> 4) << 5, tc = (t & 15) << 4;
            gtile_compute(Mtab + (size_t)mm * MATF, DD,
                          Mtab + (size_t)(p - 1) * MATF, DD, nullptr, 0.f, 0, 0,
                          Af, Bf, tr, tc, lane, acc);
            epi_plain(Mtab + (size_t)(p + mm) * MATF, DD, tr, tc, lane, acc, 0);
        }
        gridbar(bar, 3 + L);
    }

    // ph8: MTb_j[c][k] = bf16(M_j[k][c])  (32 matrices, block-cooperative)
    {
        float(*tle)[33] = (float(*)[33]) & pool[0][0];
        int tx = tid & 31, ty = tid >> 5;
        for (int it = 0; it < 8; ++it) {
            int id = blockIdx.x * 8 + it;
            int j = id >> 6, sub = id & 63;
            int k0 = (sub >> 3) << 5, c0 = (sub & 7) << 5;
            const float* M = Mtab + (size_t)j * MATF;
            unsigned short* MT = MTb + (size_t)j * MATF;
#pragma unroll
            for (int i = 0; i < 32; i += 8)
                tle[ty + i][tx] = M[(size_t)(k0 + ty + i) * DD + c0 + tx];
            __syncthreads();
#pragma unroll
            for (int i = 0; i < 32; i += 8)
                MT[(size_t)(c0 + ty + i) * DD + k0 + tx] = f2bf(tle[tx][ty + i]);
            __syncthreads();
        }
    }
    gridbar(bar, 8);

    // ph9..12: checkpoint scan. Z_i = z0@Kd^{32i} at out[:,32i-1,:] + bf16 Zb[i].
    // level s: dst = 2^s + mm from src mm (Z_0 = z0), W = Kd^{32*2^s};
    // plus one squaring job (s<3): W_{next} = W@W.
    for (int s = 0; s < 4; ++s) {
        int nvec = 1 << s;
        int njobs = nvec + (s < 3 ? 1 : 0);
        const float* W = (s == 0) ? (Mtab + (size_t)31 * MATF)
                                  : (Wtab + (size_t)(s - 1) * MATF);
        for (int tj = wgid; tj < 128 * njobs; tj += 1024) {
            int mm = tj >> 7, t = tj & 127;
            int tr = (t >> 4) << 5, tc = (t & 15) << 4;
            if (mm < nvec) {
                const float* As = mm ? (out + (size_t)(32 * mm - 1) * DD) : z0;
                size_t lda = mm ? LDT : (size_t)DD;
                gtile_compute(As, lda, W, DD, nullptr, 0.f, 0, 0, Af, Bf, tr, tc,
                              lane, acc);
                epi_v(out, Zb, nvec + mm, tr, tc, lane, acc);
            } else {
                gtile_compute(W, DD, W, DD, nullptr, 0.f, 0, 0, Af, Bf, tr, tc,
                              lane, acc);
                epi_plain(Wtab + (size_t)s * MATF, DD, tr, tc, lane, acc, 0);
            }
        }
        if (s < 3) gridbar(bar, 9 + s);
    }
}

// ---------------- batched bf16 MFMA fill (proven r2-r4 core) ----------------
// 497 jobs: i = min(bz/31,15), j = bz - i*31 + 1  (i=15 covers j=1..32 incl t=511)
__global__ void __launch_bounds__(256)
fill_kernel(const unsigned short* __restrict__ Zb,
            const unsigned short* __restrict__ MTb,
            float* __restrict__ out) {
    __shared__ __align__(16) unsigned short As[2][128 * 64];
    __shared__ __align__(16) unsigned short Bs[2][128 * 64];
    const int bz = blockIdx.z;
    const int i = (bz >= 465) ? 15 : bz / 31;
    const int j = bz - i * 31 + 1;
    const int t = i * 32 + j - 1;
    const unsigned short* Zt = Zb + (size_t)i * MATF;         // [row][k]
    const unsigned short* MT = MTb + (size_t)(j - 1) * MATF;  // [col][k]
    float* C = out + (size_t)t * DD;

    const int tid = threadIdx.x;
    const int lane = tid & 63, wid = tid >> 6;
    const int rowBase = blockIdx.y * 128, colBase = blockIdx.x * 128;
    const int wr = (wid >> 1) * 64, wc = (wid & 1) * 64;

    int rowq[4], skq[4], ldsq[4];
#pragma unroll
    for (int q = 0; q < 4; ++q) {
        int c = q * 256 + wid * 64 + lane;
        int row = c >> 3;
        rowq[q] = row;
        skq[q] = ((c ^ (row & 7)) & 7) << 3;
        ldsq[q] = (q * 256 + wid * 64) << 3;
    }

    f32x4 acc[4][4];
#pragma unroll
    for (int a = 0; a < 4; ++a)
#pragma unroll
        for (int b = 0; b < 4; ++b) acc[a][b] = (f32x4){0.f, 0.f, 0.f, 0.f};

    auto stage = [&](int buf, int k0) {
#pragma unroll
        for (int q = 0; q < 4; ++q) {
            GLD16(Zt + (size_t)(rowBase + rowq[q]) * DD + k0 + skq[q],
                  &As[buf][ldsq[q]]);
            GLD16(MT + (size_t)(colBase + rowq[q]) * DD + k0 + skq[q],
                  &Bs[buf][ldsq[q]]);
        }
    };

    stage(0, 0);
    __syncthreads();

    int cur = 0;
    for (int r = 0; r < 4; ++r) {
        if (r < 3) stage(cur ^ 1, (r + 1) * 64);
        const char* asb = (const char*)As[cur];
        const char* bsb = (const char*)Bs[cur];
#pragma unroll
        for (int ks = 0; ks < 2; ++ks) {
            bf16x8 af[4], bg[4];
            const int kk = ks * 32 + (lane >> 4) * 8;
#pragma unroll
            for (int f = 0; f < 4; ++f) {
                int rr = wr + f * 16 + (lane & 15);
                af[f] = *(const bf16x8*)(asb + ((rr * 128 + kk * 2) ^ ((rr & 7) << 4)));
                int cc = wc + f * 16 + (lane & 15);
                bg[f] = *(const bf16x8*)(bsb + ((cc * 128 + kk * 2) ^ ((cc & 7) << 4)));
            }
#pragma unroll
            for (int fr = 0; fr < 4; ++fr)
#pragma unroll
                for (int fc = 0; fc < 4; ++fc)
                    acc[fr][fc] = __builtin_amdgcn_mfma_f32_16x16x32_bf16(
                        af[fr], bg[fc], acc[fr][fc], 0, 0, 0);
        }
        __syncthreads();
        cur ^= 1;
    }

#pragma unroll
    for (int fr = 0; fr < 4; ++fr) {
        int r0 = rowBase + wr + fr * 16 + (lane >> 4) * 4;
#pragma unroll
        for (int fc = 0; fc < 4; ++fc) {
            int c = colBase + wc + fc * 16 + (lane & 15);
#pragma unroll
            for (int ii = 0; ii < 4; ++ii)
                C[(size_t)(r0 + ii) * LDT + c] = acc[fr][fc][ii];
        }
    }
}

// ---------------- fallback bits (tiny ws): proven g32 path ------------------
__global__ void prep_kernel(const float* __restrict__ K,
                            const float* __restrict__ log_dt,
                            float* __restrict__ A) {
    int idx = blockIdx.x * blockDim.x + threadIdx.x;
    A[idx] = 0.5f * expf(log_dt[0]) * K[idx];
}

__device__ __forceinline__ void g32_core(const float* Ab, int lda, const float* Bb,
                                         int ldb, int rowBase, int colBase,
                                         float acc[2][2]) {
    __shared__ __align__(16) float As[64 * 38];
    __shared__ __align__(16) float Bs[64 * 40];
    const int tid = threadIdx.x;
    const int tx = tid & 15, ty = tid >> 4;
    const int am = tid >> 4;
    const int ak = (tid & 15) << 2;
    const int bk = tid >> 3;
    const int bn = (tid & 7) << 2;
    acc[0][0] = acc[0][1] = acc[1][0] = acc[1][1] = 0.f;
    float4 pa0 = *(const float4*)(Ab + (size_t)(rowBase + am) * lda + ak);
    float4 pa1 = *(const float4*)(Ab + (size_t)(rowBase + am + 16) * lda + ak);
    float4 pb0 = *(const float4*)(Bb + (size_t)bk * ldb + colBase + bn);
    float4 pb1 = *(const float4*)(Bb + (size_t)(bk + 32) * ldb + colBase + bn);
    for (int k0 = 0; k0 < DD; k0 += 64) {
        As[(ak + 0) * 38 + am] = pa0.x;
        As[(ak + 1) * 38 + am] = pa0.y;
        As[(ak + 2) * 38 + am] = pa0.z;
        As[(ak + 3) * 38 + am] = pa0.w;
        As[(ak + 0) * 38 + am + 16] = pa1.x;
        As[(ak + 1) * 38 + am + 16] = pa1.y;
        As[(ak + 2) * 38 + am + 16] = pa1.z;
        As[(ak + 3) * 38 + am + 16] = pa1.w;
        *(float4*)(&Bs[bk * 40 + bn]) = pb0;
        *(float4*)(&Bs[(bk + 32) * 40 + bn]) = pb1;
        __syncthreads();
        if (k0 + 64 < DD) {
            pa0 = *(const float4*)(Ab + (size_t)(rowBase + am) * lda + k0 + 64 + ak);
            pa1 = *(const float4*)(Ab + (size_t)(rowBase + am + 16) * lda + k0 + 64 + ak);
            pb0 = *(const float4*)(Bb + (size_t)(bk + k0 + 64) * ldb + colBase + bn);
            pb1 = *(const float4*)(Bb + (size_t)(bk + 32 + k0 + 64) * ldb + colBase + bn);
        }
#pragma unroll
        for (int kk = 0; kk < 64; ++kk) {
            float2 a2 = *(const float2*)(&As[kk * 38 + (ty << 1)]);
            float2 b2 = *(const float2*)(&Bs[kk * 40 + (tx << 1)]);
            acc[0][0] = fmaf(a2.x, b2.x, acc[0][0]);
            acc[0][1] = fmaf(a2.x, b2.y, acc[0][1]);
            acc[1][0] = fmaf(a2.y, b2.x, acc[1][0]);
            acc[1][1] = fmaf(a2.y, b2.y, acc[1][1]);
        }
        __syncthreads();
    }
}

template <int EPI>
__global__ void __launch_bounds__(256)
g32_kernel(const float* A, const float* B, float* C, const float* E, float* C2,
           int lda, int ldb, int ldc, long long sA, long long sB, long long sC) {
    float acc[2][2];
    const int rowBase = blockIdx.y << 5, colBase = blockIdx.x << 5;
    g32_core(A + blockIdx.z * sA, lda, B + blockIdx.z * sB, ldb, rowBase, colBase, acc);
    float* Cb = C + blockIdx.z * sC;
    const int r0 = rowBase + ((threadIdx.x >> 4) << 1);
    const int c0 = colBase + ((threadIdx.x & 15) << 1);
#pragma unroll
    for (int i = 0; i < 2; ++i) {
        int r = r0 + i;
        float2 v;
        if (EPI == 2) {
            float e0 = E[(size_t)r * DD + c0], e1 = E[(size_t)r * DD + c0 + 1];
            v.x = acc[i][0] + 2.f * e0 + (r == c0 ? 1.f : 0.f);
            v.y = acc[i][1] + 2.f * e1 + (r == c0 + 1 ? 1.f : 0.f);
        } else {
            v.x = acc[i][0];
            v.y = acc[i][1];
        }
        *(float2*)(Cb + (size_t)r * ldc + c0) = v;
        if (EPI == 1) {
            float e0 = E[(size_t)r * DD + c0], e1 = E[(size_t)r * DD + c0 + 1];
            float2 w;
            w.x = 2.f * acc[i][0] + 2.f * e0 + (r == c0 ? 2.f : 0.f);
            w.y = 2.f * acc[i][1] + 2.f * e1 + (r == c0 + 1 ? 2.f : 0.f);
            *(float2*)(C2 + (size_t)r * DD + c0) = w;
        }
    }
}

// ---------------- launch ----------------------------------------------------
extern "C" void kernel_launch(void* const* d_in, const int* in_sizes, int n_in,
                              void* d_out, int out_size, void* d_ws, size_t ws_size,
                              hipStream_t stream) {
    const float* z0 = (const float*)d_in[0];
    const float* Kmat = (const float*)d_in[1];
    const float* log_dt = (const float*)d_in[2];
    float* out = (float*)d_out;

    dim3 blk(256);

    // ws: Mtab[32] | Wtab[3] | P | MTb[32] bf16 | Zb[16] bf16 | bar[257]
    float* Mtab = (float*)d_ws;
    float* Wtab = Mtab + (size_t)32 * MATF;
    float* Pmat = Wtab + (size_t)3 * MATF;
    unsigned short* MTb = (unsigned short*)(Pmat + MATF);
    unsigned short* Zb = MTb + (size_t)32 * MATF;
    unsigned* bar = (unsigned*)(Zb + (size_t)16 * MATF);
    const size_t need =
        (size_t)36 * MATF * 4 + (size_t)48 * MATF * 2 + 2048;

    if (ws_size >= need) {
        binit_kernel<<<1, 320, 0, stream>>>(bar);
        tabs_kernel<<<256, blk, 0, stream>>>(z0, Kmat, log_dt, out, Mtab, Wtab,
                                             Pmat, MTb, Zb, bar);
        fill_kernel<<<dim3(2, 2, 497), blk, 0, stream>>>(Zb, MTb, out);
        return;
    }

    // Minimal fallback (tiny ws): Kd then 512 chained GEMMs (f32, proven core).
    float* A = (float*)d_ws;
    float* A2 = A + MATF;
    float* Bop = A2 + MATF;
    float* Kd = Bop + MATF;
    prep_kernel<<<MATF / 256, blk, 0, stream>>>(Kmat, log_dt, A);
    dim3 g(8, 8, 1);
    g32_kernel<1><<<g, blk, 0, stream>>>(A, A, A2, A, Bop, DD, DD, DD, 0, 0, 0);
    g32_kernel<2><<<g, blk, 0, stream>>>(A2, Bop, Kd, A, (float*)0, DD, DD, DD, 0, 0, 0);
    for (int t = 0; t < TT; ++t) {
        const float* Ain = (t == 0) ? z0 : out + (size_t)(t - 1) * DD;
        int lda = (t == 0) ? DD : TT * DD;
        g32_kernel<0><<<g, blk, 0, stream>>>(Ain, Kd, out + (size_t)t * DD,
                                             (const float*)0, (float*)0,
                                             lda, DD, TT * DD, 0, 0, 0);
    }
}

// Round 6
// 151.814 us; speedup vs baseline: 2.6842x; 2.6842x over previous
//
#include <hip/hip_runtime.h>

// Koopman bilinear rollout: preds[b,t,d] = (z0 @ Kd^{t+1})[b,d], D=B=256, T=512.
// Kd = (I-A)^-1(I+A), A=0.5*dt*K -> order-4 Neumann (2 GEMM launches, proven).
// M_j=Kd^j (j=1..32, 5 doubling launches), checkpoint scan (4 batched launches:
// Z_{2^s+m} = Z_m @ Kd^{32*2^s} with the W-squaring folded into the batch),
// then ONE batched bf16-MFMA fill for the remaining 497 timesteps.
// Fill: global_load_lds staging (proven r4) + NEW LDS-staged coalesced C-write
// (replaces 64 scattered scalar stores/lane with 16 dwordx4 row-segment stores).
// NOTE (r5 post-mortem): persistent kernel + agent-scope spin barrier = 392us
// (acquire-polling invalidates L2 continuously). Do NOT retry grid barriers.

#define DD 256
#define TT 512
#define MATF (DD * DD)
#define LDT ((size_t)TT * (size_t)DD)

typedef __attribute__((ext_vector_type(8))) short bf16x8;
typedef __attribute__((ext_vector_type(4))) float f32x4;

#define GLD16(g, l)                                                  \
    __builtin_amdgcn_global_load_lds(                                \
        (const __attribute__((address_space(1))) void*)(g),          \
        (__attribute__((address_space(3))) void*)(l), 16, 0, 0)

static __device__ __forceinline__ unsigned short f2bf(float f) {
    unsigned int u = __float_as_uint(f);
    u += 0x7fffu + ((u >> 16) & 1u);
    return (unsigned short)(u >> 16);
}

// A = 0.5*exp(log_dt)*K ; Zb0 = bf16(z0)
__global__ void prep_kernel(const float* __restrict__ K,
                            const float* __restrict__ log_dt,
                            const float* __restrict__ z0,
                            float* __restrict__ A,
                            unsigned short* __restrict__ Zb0) {
    int idx = blockIdx.x * blockDim.x + threadIdx.x;
    float c = 0.5f * expf(log_dt[0]);
    A[idx] = c * K[idx];
    if (Zb0) Zb0[idx] = f2bf(z0[idx]);
}

// MTb_j[c][k] = bf16(M_j[k][c])  (transpose+convert, 32x32 LDS tiles)
__global__ void mtrans_kernel(const float* __restrict__ Mtab,
                              unsigned short* __restrict__ MTb) {
    __shared__ float tle[32][33];
    int j = blockIdx.z;
    const float* M = Mtab + (size_t)j * MATF;
    unsigned short* MT = MTb + (size_t)j * MATF;
    int k0 = blockIdx.y * 32, c0 = blockIdx.x * 32;
    int tx = threadIdx.x, ty = threadIdx.y;  // 32 x 8
#pragma unroll
    for (int i = 0; i < 32; i += 8)
        tle[ty + i][tx] = M[(size_t)(k0 + ty + i) * DD + c0 + tx];
    __syncthreads();
#pragma unroll
    for (int i = 0; i < 32; i += 8)
        MT[(size_t)(c0 + ty + i) * DD + k0 + tx] = f2bf(tle[tx][ty + i]);
}

// ---- 32x32-tile f32 GEMM core: 256 threads, K=256, K_BLK=64, reg prefetch ----
__device__ __forceinline__ void g32_core(const float* __restrict__ Ab, int lda,
                                         const float* __restrict__ Bb, int ldb,
                                         int rowBase, int colBase, float acc[2][2]) {
    __shared__ __align__(16) float As[64 * 38];
    __shared__ __align__(16) float Bs[64 * 40];
    const int tid = threadIdx.x;
    const int tx = tid & 15, ty = tid >> 4;
    const int am = tid >> 4;
    const int ak = (tid & 15) << 2;
    const int bk = tid >> 3;
    const int bn = (tid & 7) << 2;

    acc[0][0] = acc[0][1] = acc[1][0] = acc[1][1] = 0.f;

    float4 pa0 = *(const float4*)(Ab + (size_t)(rowBase + am) * lda + ak);
    float4 pa1 = *(const float4*)(Ab + (size_t)(rowBase + am + 16) * lda + ak);
    float4 pb0 = *(const float4*)(Bb + (size_t)bk * ldb + colBase + bn);
    float4 pb1 = *(const float4*)(Bb + (size_t)(bk + 32) * ldb + colBase + bn);

    for (int k0 = 0; k0 < DD; k0 += 64) {
        As[(ak + 0) * 38 + am] = pa0.x;
        As[(ak + 1) * 38 + am] = pa0.y;
        As[(ak + 2) * 38 + am] = pa0.z;
        As[(ak + 3) * 38 + am] = pa0.w;
        As[(ak + 0) * 38 + am + 16] = pa1.x;
        As[(ak + 1) * 38 + am + 16] = pa1.y;
        As[(ak + 2) * 38 + am + 16] = pa1.z;
        As[(ak + 3) * 38 + am + 16] = pa1.w;
        *(float4*)(&Bs[bk * 40 + bn]) = pb0;
        *(float4*)(&Bs[(bk + 32) * 40 + bn]) = pb1;
        __syncthreads();
        if (k0 + 64 < DD) {
            pa0 = *(const float4*)(Ab + (size_t)(rowBase + am) * lda + k0 + 64 + ak);
            pa1 = *(const float4*)(Ab + (size_t)(rowBase + am + 16) * lda + k0 + 64 + ak);
            pb0 = *(const float4*)(Bb + (size_t)(bk + k0 + 64) * ldb + colBase + bn);
            pb1 = *(const float4*)(Bb + (size_t)(bk + 32 + k0 + 64) * ldb + colBase + bn);
        }
#pragma unroll
        for (int kk = 0; kk < 64; ++kk) {
            float2 a2 = *(const float2*)(&As[kk * 38 + (ty << 1)]);
            float2 b2 = *(const float2*)(&Bs[kk * 40 + (tx << 1)]);
            acc[0][0] = fmaf(a2.x, b2.x, acc[0][0]);
            acc[0][1] = fmaf(a2.x, b2.y, acc[0][1]);
            acc[1][0] = fmaf(a2.y, b2.x, acc[1][0]);
            acc[1][1] = fmaf(a2.y, b2.y, acc[1][1]);
        }
        __syncthreads();
    }
}

// EPI 0: C = acc
// EPI 1: C = acc (=A@A) ; C2 = 2I + 2E + 2acc   (Neumann stage 1, E = A)
// EPI 2: C = acc + I + 2E                        (Neumann stage 2, E = A)
template <int EPI>
__global__ void __launch_bounds__(256)
g32_kernel(const float* __restrict__ A, const float* __restrict__ B,
           float* __restrict__ C, const float* __restrict__ E,
           float* __restrict__ C2,
           int lda, int ldb, int ldc,
           long long sA, long long sB, long long sC) {
    float acc[2][2];
    const int rowBase = blockIdx.y << 5, colBase = blockIdx.x << 5;
    g32_core(A + blockIdx.z * sA, lda, B + blockIdx.z * sB, ldb, rowBase, colBase, acc);
    float* Cb = C + blockIdx.z * sC;
    const int r0 = rowBase + ((threadIdx.x >> 4) << 1);
    const int c0 = colBase + ((threadIdx.x & 15) << 1);
#pragma unroll
    for (int i = 0; i < 2; ++i) {
        int r = r0 + i;
        float2 v;
        if (EPI == 2) {
            float e0 = E[(size_t)r * DD + c0], e1 = E[(size_t)r * DD + c0 + 1];
            v.x = acc[i][0] + 2.f * e0 + (r == c0 ? 1.f : 0.f);
            v.y = acc[i][1] + 2.f * e1 + (r == c0 + 1 ? 1.f : 0.f);
        } else {
            v.x = acc[i][0];
            v.y = acc[i][1];
        }
        *(float2*)(Cb + (size_t)r * ldc + c0) = v;
        if (EPI == 1) {
            float e0 = E[(size_t)r * DD + c0], e1 = E[(size_t)r * DD + c0 + 1];
            float2 w;
            w.x = 2.f * acc[i][0] + 2.f * e0 + (r == c0 ? 2.f : 0.f);
            w.y = 2.f * acc[i][1] + 2.f * e1 + (r == c0 + 1 ? 2.f : 0.f);
            *(float2*)(C2 + (size_t)r * DD + c0) = w;
        }
    }
}

// Checkpoint scan level s (batched): jobs mm < 2^s are Z-jobs
//   Z_{2^s+mm} = Z_mm @ W_{2^s}  (Z_0 = z0) -> f32 out[:,32*dst-1,:] + bf16 Zb[dst]
// job mm == 2^s (levels s<3) squares W: Wtab[s] = W_{2^s} @ W_{2^s}.
// W_1 = Mtab[31] (= Kd^32); W_{2^s} = Wtab[s-1] for s>=1.
__global__ void __launch_bounds__(256)
scan_kernel(const float* __restrict__ z0, float* __restrict__ out,
            const float* __restrict__ M32, float* __restrict__ Wtab,
            unsigned short* __restrict__ Zb, int s) {
    const int nvec = 1 << s;
    const int mm = blockIdx.z;
    const float* W = (s == 0) ? M32 : Wtab + (size_t)(s - 1) * MATF;
    float acc[2][2];
    const int rowBase = blockIdx.y << 5, colBase = blockIdx.x << 5;
    const int r0 = rowBase + ((threadIdx.x >> 4) << 1);
    const int c0 = colBase + ((threadIdx.x & 15) << 1);
    if (mm < nvec) {
        const float* Asrc = mm ? out + (size_t)(32 * mm - 1) * DD : z0;
        int lda = mm ? (int)LDT : DD;
        g32_core(Asrc, lda, W, DD, rowBase, colBase, acc);
        const int dst = nvec + mm;  // 1..15
        float* Of = out + (size_t)(32 * dst - 1) * DD;
        unsigned short* Zo = Zb + (size_t)dst * MATF;
#pragma unroll
        for (int ii = 0; ii < 2; ++ii) {
            int r = r0 + ii;
            float2 v = {acc[ii][0], acc[ii][1]};
            *(float2*)(Of + (size_t)r * LDT + c0) = v;
            unsigned w = (unsigned)f2bf(v.x) | ((unsigned)f2bf(v.y) << 16);
            *(unsigned*)(Zo + (size_t)r * DD + c0) = w;
        }
    } else {
        g32_core(W, DD, W, DD, rowBase, colBase, acc);
        float* Cb = Wtab + (size_t)s * MATF;
#pragma unroll
        for (int ii = 0; ii < 2; ++ii) {
            int r = r0 + ii;
            float2 v = {acc[ii][0], acc[ii][1]};
            *(float2*)(Cb + (size_t)r * DD + c0) = v;
        }
    }
}

// Batched bf16 MFMA fill: 497 jobs; i = min(bz/31,15), j = bz - i*31 + 1
// (i<15: j=1..31; i=15: j=1..32 incl. t=511). out[:, 32i+j-1, :] = Zb[i] @ M_j.
// 128x128 tile, 4 waves, dbuf global_load_lds staging (proven r4), then
// LDS-staged C write: acc -> Cs (64KB pool reuse, 2-way-swizzled banks) ->
// coalesced 512B row segments via dwordx4.
__global__ void __launch_bounds__(256)
fill_kernel(const unsigned short* __restrict__ Zb,
            const unsigned short* __restrict__ MTb,
            float* __restrict__ out) {
    __shared__ __align__(16) char pool[65536];  // A dbuf 32K | B dbuf 32K ; C reuse
    const int bz = blockIdx.z;
    const int i = (bz >= 465) ? 15 : bz / 31;
    const int j = bz - i * 31 + 1;
    const int t = i * 32 + j - 1;
    const unsigned short* Zt = Zb + (size_t)i * MATF;         // [row][k]
    const unsigned short* MT = MTb + (size_t)(j - 1) * MATF;  // [col][k]

    const int tid = threadIdx.x;
    const int lane = tid & 63, wid = tid >> 6;
    const int rowBase = blockIdx.y * 128, colBase = blockIdx.x * 128;
    const int wr = (wid >> 1) * 64, wc = (wid & 1) * 64;

    int rowq[4], skq[4], ldsb[4];
#pragma unroll
    for (int q = 0; q < 4; ++q) {
        int c = q * 256 + wid * 64 + lane;
        int row = c >> 3;
        rowq[q] = row;
        skq[q] = ((c ^ (row & 7)) & 7) << 3;  // pre-swizzled src k-offset
        ldsb[q] = (q * 256 + wid * 64) << 4;  // wave-uniform LDS byte base
    }

    f32x4 acc[4][4];
#pragma unroll
    for (int a = 0; a < 4; ++a)
#pragma unroll
        for (int b = 0; b < 4; ++b) acc[a][b] = (f32x4){0.f, 0.f, 0.f, 0.f};

    auto stage = [&](int buf, int k0) {
        char* ab = pool + buf * 16384;
        char* bb = pool + 32768 + buf * 16384;
#pragma unroll
        for (int q = 0; q < 4; ++q) {
            GLD16(Zt + (size_t)(rowBase + rowq[q]) * DD + k0 + skq[q], ab + ldsb[q]);
            GLD16(MT + (size_t)(colBase + rowq[q]) * DD + k0 + skq[q], bb + ldsb[q]);
        }
    };

    stage(0, 0);
    __syncthreads();

    int cur = 0;
    for (int r = 0; r < 4; ++r) {
        if (r < 3) stage(cur ^ 1, (r + 1) * 64);
        const char* asb = pool + cur * 16384;
        const char* bsb = pool + 32768 + cur * 16384;
#pragma unroll
        for (int ks = 0; ks < 2; ++ks) {
            bf16x8 af[4], bg[4];
            const int kk = ks * 32 + (lane >> 4) * 8;
#pragma unroll
            for (int f = 0; f < 4; ++f) {
                int rr = wr + f * 16 + (lane & 15);
                af[f] = *(const bf16x8*)(asb + ((rr * 128 + kk * 2) ^ ((rr & 7) << 4)));
                int cc = wc + f * 16 + (lane & 15);
                bg[f] = *(const bf16x8*)(bsb + ((cc * 128 + kk * 2) ^ ((cc & 7) << 4)));
            }
#pragma unroll
            for (int fr = 0; fr < 4; ++fr)
#pragma unroll
                for (int fc = 0; fc < 4; ++fc)
                    acc[fr][fc] = __builtin_amdgcn_mfma_f32_16x16x32_bf16(
                        af[fr], bg[fc], acc[fr][fc], 0, 0, 0);
        }
        __syncthreads();
        cur ^= 1;
    }

    // ---- C epilogue: stage tile in LDS, then coalesced dwordx4 stores ----
    float* Cs = (float*)pool;  // 128 x 128 f32 = 64KB (K-loop done, safe)
#pragma unroll
    for (int fr = 0; fr < 4; ++fr) {
#pragma unroll
        for (int fc = 0; fc < 4; ++fc) {
            int ccol = wc + fc * 16 + (lane & 15);
#pragma unroll
            for (int ii = 0; ii < 4; ++ii) {
                int r = wr + fr * 16 + ((lane >> 4) << 2) + ii;
                // spread the 4 row-groups across 2 bank halves (2-way = free)
                int csw = ccol ^ (((r >> 2) & 1) << 4);
                Cs[r * 128 + csw] = acc[fr][fc][ii];
            }
        }
    }
    __syncthreads();
    float* C = out + (size_t)t * DD;
#pragma unroll
    for (int it = 0; it < 16; ++it) {
        int chunk = it * 256 + tid;
        int row = chunk >> 5;
        int c4 = (chunk & 31) << 2;
        int csw = c4 ^ (((row >> 2) & 1) << 4);
        float4 v = *(const float4*)(Cs + row * 128 + csw);
        *(float4*)(C + (size_t)(rowBase + row) * LDT + colBase + c4) = v;
    }
}

// ---------------- launch ----------------------------------------------------
extern "C" void kernel_launch(void* const* d_in, const int* in_sizes, int n_in,
                              void* d_out, int out_size, void* d_ws, size_t ws_size,
                              hipStream_t stream) {
    const float* z0 = (const float*)d_in[0];
    const float* Kmat = (const float*)d_in[1];
    const float* log_dt = (const float*)d_in[2];
    float* out = (float*)d_out;

    dim3 blk(256);

    // ws: A | A2 | Bop | Mtab[32] | Wtab[3] f32 | MTb[32] bf16 | Zb[16] bf16
    float* A = (float*)d_ws;
    float* A2 = A + MATF;
    float* Bop = A2 + MATF;
    float* Mtab = Bop + MATF;
    float* Wtab = Mtab + (size_t)32 * MATF;
    unsigned short* MTb = (unsigned short*)(Wtab + (size_t)3 * MATF);
    unsigned short* Zb = MTb + (size_t)32 * MATF;
    const size_t need = (size_t)38 * MATF * 4 + (size_t)48 * MATF * 2;

    if (ws_size >= need) {
        prep_kernel<<<MATF / 256, blk, 0, stream>>>(Kmat, log_dt, z0, A, Zb);

        dim3 g(8, 8, 1);
        // Neumann (order 4): A2 = A@A (+Bop epi); Kd = A2@Bop + I + 2A -> Mtab[0]
        g32_kernel<1><<<g, blk, 0, stream>>>(A, A, A2, A, Bop, DD, DD, DD, 0, 0, 0);
        g32_kernel<2><<<g, blk, 0, stream>>>(A2, Bop, Mtab, A, (float*)0,
                                             DD, DD, DD, 0, 0, 0);

        // M powers: M_{q+p} = M_q @ M_p (log depth) -> M_1..M_32
        for (int p = 1; p < 32; p <<= 1)
            g32_kernel<0><<<dim3(8, 8, p), blk, 0, stream>>>(
                Mtab, Mtab + (size_t)(p - 1) * MATF, Mtab + (size_t)p * MATF,
                (const float*)0, (float*)0, DD, DD, DD, MATF, 0, MATF);

        // bf16 transposed M table (j=1..32)
        mtrans_kernel<<<dim3(8, 8, 32), dim3(32, 8), 0, stream>>>(Mtab, MTb);

        // checkpoint scan: 4 batched levels (Z-jobs + W-squaring per level)
        const int njobs[4] = {2, 3, 5, 8};
        for (int s = 0; s < 4; ++s)
            scan_kernel<<<dim3(8, 8, njobs[s]), blk, 0, stream>>>(
                z0, out, Mtab + (size_t)31 * MATF, Wtab, Zb, s);

        // All 497 remaining timesteps in one batched MFMA launch
        fill_kernel<<<dim3(2, 2, 497), blk, 0, stream>>>(Zb, MTb, out);
        return;
    }

    // Minimal fallback (tiny ws): Kd then 512 chained GEMMs (f32, proven core).
    float* Kd = Bop + MATF;
    prep_kernel<<<MATF / 256, blk, 0, stream>>>(Kmat, log_dt, z0, A,
                                                (unsigned short*)0);
    dim3 g(8, 8, 1);
    g32_kernel<1><<<g, blk, 0, stream>>>(A, A, A2, A, Bop, DD, DD, DD, 0, 0, 0);
    g32_kernel<2><<<g, blk, 0, stream>>>(A2, Bop, Kd, A, (float*)0, DD, DD, DD, 0, 0, 0);
    for (int t = 0; t < TT; ++t) {
        const float* Ain = (t == 0) ? z0 : out + (size_t)(t - 1) * DD;
        int lda = (t == 0) ? DD : (int)LDT;
        g32_kernel<0><<<g, blk, 0, stream>>>(Ain, Kd, out + (size_t)t * DD,
                                             (const float*)0, (float*)0,
                                             lda, DD, (int)LDT, 0, 0, 0);
    }
}